// Round 2
// baseline (1058.304 us; speedup 1.0000x reference)
//
#include <hip/hip_runtime.h>
#include <cmath>

#define B_ 64
#define L_ 200
#define H_ 128
#define S_ 64
#define E_ 256
#define K_ 101
#define NROW (B_ * L_)

__device__ __forceinline__ float wave_sum64(float v) {
#pragma unroll
  for (int o = 32; o > 0; o >>= 1) v += __shfl_xor(v, o, 64);
  return v;
}

__device__ __forceinline__ float block_sum_256(float v, volatile float* red) {
  v = wave_sum64(v);
  int w = threadIdx.x >> 6;
  __syncthreads();  // protect red reuse across calls
  if ((threadIdx.x & 63) == 0) red[w] = v;
  __syncthreads();
  return red[0] + red[1] + red[2] + red[3];
}

// x[b,l,h] = (item_emb[seq] + pos_emb[l]) * mask
__global__ void embed_kernel(const int* __restrict__ seqs, const float* __restrict__ emb,
                             const float* __restrict__ pos, float* __restrict__ x) {
  int r = blockIdx.x;          // b*L + l
  int h = threadIdx.x;         // 128
  int l = r % L_;
  int idx = seqs[r];
  float val = (idx != 0) ? (emb[(size_t)idx * H_ + h] + pos[l * H_ + h]) : 0.f;
  x[(size_t)r * H_ + h] = val;
}

// LayerNorm over H=128, one wave per row (2 elems/thread)
__global__ void ln_h_kernel(const float* __restrict__ x, const float* __restrict__ g,
                            const float* __restrict__ b, float* __restrict__ u) {
  int r = blockIdx.x;
  int t = threadIdx.x;  // 64
  float v0 = x[(size_t)r * H_ + t];
  float v1 = x[(size_t)r * H_ + 64 + t];
  float mean = wave_sum64(v0 + v1) * (1.f / 128.f);
  float d0 = v0 - mean, d1 = v1 - mean;
  float var = wave_sum64(d0 * d0 + d1 * d1) * (1.f / 128.f);
  float rs = rsqrtf(var + 1e-5f);
  u[(size_t)r * H_ + t]      = d0 * rs * g[t] + b[t];
  u[(size_t)r * H_ + 64 + t] = d1 * rs * g[64 + t] + b[64 + t];
}

// Final LN only at l = L-1, write xf[b,H]
__global__ void ln_final_kernel(const float* __restrict__ x, const float* __restrict__ g,
                                const float* __restrict__ b, float* __restrict__ xf) {
  int bb = blockIdx.x;
  int t = threadIdx.x;  // 64
  size_t r = (size_t)bb * L_ + (L_ - 1);
  float v0 = x[r * H_ + t];
  float v1 = x[r * H_ + 64 + t];
  float mean = wave_sum64(v0 + v1) * (1.f / 128.f);
  float d0 = v0 - mean, d1 = v1 - mean;
  float var = wave_sum64(d0 * d0 + d1 * d1) * (1.f / 128.f);
  float rs = rsqrtf(var + 1e-5f);
  xf[bb * H_ + t]      = d0 * rs * g[t] + b[t];
  xf[bb * H_ + 64 + t] = d1 * rs * g[64 + t] + b[64 + t];
}

// Tiled fp32 GEMM: C[M,N] = A[M,K] @ W[K,N] + bias
// EPI==1: C = (C_old + val) * mask[row]  (residual+mask epilogue)
template <int EPI>
__global__ __launch_bounds__(256) void gemm_kernel(
    const float* __restrict__ A, const float* __restrict__ W,
    const float* __restrict__ bias, float* __restrict__ C,
    int M, int N, int K, const int* __restrict__ seqs) {
  __shared__ float As[64][20];  // [m][k], pad to 20 for aligned float4 stores
  __shared__ float Bs[16][64];  // [k][n]
  const int tid = threadIdx.x;
  const int tx = tid & 15;   // n-dir
  const int ty = tid >> 4;   // m-dir
  const int m0 = blockIdx.y * 64;
  const int n0 = blockIdx.x * 64;

  const int a_m = tid >> 2;
  const int a_k = (tid & 3) << 2;
  const int b_k = tid >> 4;
  const int b_n = (tid & 15) << 2;

  float acc[4][4] = {{0.f, 0.f, 0.f, 0.f}, {0.f, 0.f, 0.f, 0.f},
                     {0.f, 0.f, 0.f, 0.f}, {0.f, 0.f, 0.f, 0.f}};

  for (int k0 = 0; k0 < K; k0 += 16) {
    float4 av = *(const float4*)(A + (size_t)(m0 + a_m) * K + k0 + a_k);
    float4 bv = *(const float4*)(W + (size_t)(b_k + k0) * N + n0 + b_n);
    *(float4*)&As[a_m][a_k] = av;
    *(float4*)&Bs[b_k][b_n] = bv;
    __syncthreads();
#pragma unroll
    for (int kk = 0; kk < 16; ++kk) {
      float4 b4 = *(const float4*)&Bs[kk][tx << 2];
      float a0 = As[ty * 4 + 0][kk];
      float a1 = As[ty * 4 + 1][kk];
      float a2 = As[ty * 4 + 2][kk];
      float a3 = As[ty * 4 + 3][kk];
      acc[0][0] += a0 * b4.x; acc[0][1] += a0 * b4.y; acc[0][2] += a0 * b4.z; acc[0][3] += a0 * b4.w;
      acc[1][0] += a1 * b4.x; acc[1][1] += a1 * b4.y; acc[1][2] += a1 * b4.z; acc[1][3] += a1 * b4.w;
      acc[2][0] += a2 * b4.x; acc[2][1] += a2 * b4.y; acc[2][2] += a2 * b4.z; acc[2][3] += a2 * b4.w;
      acc[3][0] += a3 * b4.x; acc[3][1] += a3 * b4.y; acc[3][2] += a3 * b4.z; acc[3][3] += a3 * b4.w;
    }
    __syncthreads();
  }

  float4 bz = *(const float4*)(bias + n0 + (tx << 2));
#pragma unroll
  for (int i = 0; i < 4; ++i) {
    int row = m0 + ty * 4 + i;
    float* cp = C + (size_t)row * N + n0 + (tx << 2);
    float4 val;
    val.x = acc[i][0] + bz.x;
    val.y = acc[i][1] + bz.y;
    val.z = acc[i][2] + bz.z;
    val.w = acc[i][3] + bz.w;
    if (EPI == 1) {
      float msk = (seqs[row] != 0) ? 1.f : 0.f;
      float4 old = *(const float4*)cp;
      val.x = (old.x + val.x) * msk;
      val.y = (old.y + val.y) * msk;
      val.z = (old.z + val.z) * msk;
      val.w = (old.w + val.w) * msk;
    }
    *(float4*)cp = val;
  }
}

// Depthwise conv (k=3, symmetric pad 1, cross-correlation) + bias + silu.
__global__ void conv_silu_kernel(const float* __restrict__ xz, const float* __restrict__ cw,
                                 const float* __restrict__ cb, float* __restrict__ xc,
                                 float* __restrict__ xsum) {
  __shared__ float red[4];
  int r = blockIdx.x;   // b*L + l
  int e = threadIdx.x;  // 256
  int l = r % L_;
  float w0 = cw[e * 3 + 0], w1 = cw[e * 3 + 1], w2 = cw[e * 3 + 2];
  float xm1 = (l > 0)      ? xz[(size_t)(r - 1) * 512 + e] : 0.f;
  float x0  =                xz[(size_t)r * 512 + e];
  float xp1 = (l < L_ - 1) ? xz[(size_t)(r + 1) * 512 + e] : 0.f;
  float v = w0 * xm1 + w1 * x0 + w2 * xp1 + cb[e];
  float sv = v / (1.f + expf(-v));  // silu
  xc[(size_t)r * E_ + e] = sv;
  float tot = block_sum_256(sv, red);
  if (threadIdx.x == 0) xsum[r] = tot;
}

// Sequential scan, collapsed state h[S] per batch. One WAVE per batch, no
// barriers. Lane i owns h_i; inner matvec broadcasts h_j/A2_j via readlane.
// exp folded to v_exp_f32: A2 = A*log2e, clip bound -10*log2e.
__global__ __launch_bounds__(64) void scan_kernel(
    const float* __restrict__ ssm,   // [B*L, 192]: delta_raw | Bm | Cm
    const float* __restrict__ xs,    // [B*L]
    const float* __restrict__ A_log, // [S] (block-offset applied by caller)
    float* __restrict__ s_out) {     // [B*L]
  const int b = blockIdx.x;
  const int i = threadIdx.x;  // 64
  const float LOG2E = 1.44269504088896340736f;
  const float LB = -14.4269504088896340736f;  // -10*log2e

  float al = fminf(fmaxf(A_log[i], -5.f), 5.f);
  float A2 = -expf(al) * LOG2E;  // lane j holds A2_j
  float h = 0.f;                 // lane i holds h_i

  const float* base = ssm + (size_t)b * L_ * 192;
  const float* xsb = xs + b * L_;

  // prefetch step 0
  float dr = base[i], bm = base[64 + i], cm = base[128 + i], xst = xsb[0];

  for (int t = 0; t < L_; ++t) {
    // prefetch step t+1 (independent of h -> hidden under j-loop)
    float dr2 = 0.f, bm2 = 0.f, cm2 = 0.f, xst2 = 0.f;
    if (t + 1 < L_) {
      const float* r2 = base + (size_t)(t + 1) * 192;
      dr2 = r2[i]; bm2 = r2[64 + i]; cm2 = r2[128 + i]; xst2 = xsb[t + 1];
    }
    // softplus(delta_raw)
    float d = fmaxf(dr, 0.f) + log1pf(__expf(-fabsf(dr)));
    float acc = d * bm * xst;  // dB_i * xsum contribution
#pragma unroll
    for (int j = 0; j < 64; ++j) {
      float a2j = __int_as_float(__builtin_amdgcn_readlane(__float_as_int(A2), j));
      float hj  = __int_as_float(__builtin_amdgcn_readlane(__float_as_int(h), j));
      float e = fmaxf(d * a2j, LB);
      acc += __builtin_amdgcn_exp2f(e) * hj;
    }
    h = fminf(fmaxf(acc, -100.f), 100.f);
    float y = wave_sum64(h * cm);
    if (i == 0) s_out[b * L_ + t] = y;
    dr = dr2; bm = bm2; cm = cm2; xst = xst2;
  }
}

// y = s + D*xc ; yln = LN_E(y) ; v = yln * silu(z)
__global__ void gate_kernel(const float* __restrict__ s, const float* __restrict__ xc,
                            const float* __restrict__ xz, const float* __restrict__ D,
                            const float* __restrict__ g, const float* __restrict__ bb,
                            float* __restrict__ v) {
  __shared__ float red[4];
  int r = blockIdx.x;
  int e = threadIdx.x;  // 256
  float y = s[r] + D[e] * xc[(size_t)r * E_ + e];
  float mean = block_sum_256(y, red) * (1.f / 256.f);
  float d = y - mean;
  float var = block_sum_256(d * d, red) * (1.f / 256.f);
  float yln = d * rsqrtf(var + 1e-5f) * g[e] + bb[e];
  float z = xz[(size_t)r * 512 + 256 + e];
  v[(size_t)r * E_ + e] = yln * (z / (1.f + expf(-z)));
}

// logits[b,k] = xf[b,:] . item_emb[item_idxs[b,k], :]
__global__ void logits_kernel(const float* __restrict__ xf, const int* __restrict__ idxs,
                              const float* __restrict__ emb, float* __restrict__ out) {
  int p = blockIdx.x;  // b*K + k
  int b = p / K_;
  int t = threadIdx.x;  // 64
  int id = idxs[p];
  float a = xf[b * H_ + t] * emb[(size_t)id * H_ + t] +
            xf[b * H_ + 64 + t] * emb[(size_t)id * H_ + 64 + t];
  a = wave_sum64(a);
  if (t == 0) out[p] = a;
}

extern "C" void kernel_launch(void* const* d_in, const int* in_sizes, int n_in,
                              void* d_out, int out_size, void* d_ws, size_t ws_size,
                              hipStream_t stream) {
  const int*   seqs   = (const int*)d_in[0];
  const int*   idxs   = (const int*)d_in[1];
  const float* emb    = (const float*)d_in[2];
  const float* pos    = (const float*)d_in[3];
  const float* blk_g  = (const float*)d_in[4];
  const float* blk_b  = (const float*)d_in[5];
  const float* in_w   = (const float*)d_in[6];
  const float* in_b   = (const float*)d_in[7];
  const float* conv_w = (const float*)d_in[8];
  const float* conv_b = (const float*)d_in[9];
  const float* xp_w   = (const float*)d_in[10];
  const float* xp_b   = (const float*)d_in[11];
  const float* A_log  = (const float*)d_in[12];
  const float* D_p    = (const float*)d_in[13];
  const float* out_w  = (const float*)d_in[14];
  const float* out_b  = (const float*)d_in[15];
  const float* ig     = (const float*)d_in[16];
  const float* ib     = (const float*)d_in[17];
  const float* fg     = (const float*)d_in[18];
  const float* fb     = (const float*)d_in[19];
  float* out = (float*)d_out;
  float* ws = (float*)d_ws;

  float* x   = ws;               // [12800,128]
  float* u   = ws + 1638400;     // [12800,128]
  float* xz  = ws + 3276800;     // [12800,512]
  float* xc  = ws + 9830400;     // [12800,256]
  float* ssm = ws + 13107200;    // [12800,192]
  float* v   = ws + 15564800;    // [12800,256]
  float* xs  = ws + 18841600;    // [12800]
  float* sA  = ws + 18854400;    // [12800]
  float* xf  = ws + 18867200;    // [64,128]

  embed_kernel<<<NROW, 128, 0, stream>>>(seqs, emb, pos, x);

  for (int blk = 0; blk < 2; ++blk) {
    ln_h_kernel<<<NROW, 64, 0, stream>>>(x, blk_g + blk * H_, blk_b + blk * H_, u);
    gemm_kernel<0><<<dim3(512 / 64, NROW / 64), 256, 0, stream>>>(
        u, in_w + (size_t)blk * H_ * 2 * E_, in_b + blk * 2 * E_, xz, NROW, 512, 128, nullptr);
    conv_silu_kernel<<<NROW, 256, 0, stream>>>(xz, conv_w + blk * E_ * 3, conv_b + blk * E_,
                                               xc, xs);
    gemm_kernel<0><<<dim3(192 / 64, NROW / 64), 256, 0, stream>>>(
        xc, xp_w + (size_t)blk * E_ * 3 * S_, xp_b + blk * 3 * S_, ssm, NROW, 192, 256, nullptr);
    scan_kernel<<<B_, 64, 0, stream>>>(ssm, xs, A_log + blk * S_, sA);
    gate_kernel<<<NROW, 256, 0, stream>>>(sA, xc, xz, D_p + blk * E_, ig + blk * E_,
                                          ib + blk * E_, v);
    gemm_kernel<1><<<dim3(128 / 64, NROW / 64), 256, 0, stream>>>(
        v, out_w + (size_t)blk * E_ * H_, out_b + blk * H_, x, NROW, 128, 256, seqs);
  }

  ln_final_kernel<<<B_, 64, 0, stream>>>(x, fg, fb, xf);
  logits_kernel<<<B_ * K_, 64, 0, stream>>>(xf, idxs, emb, out);
}

// Round 3
// 748.985 us; speedup vs baseline: 1.4130x; 1.4130x over previous
//
#include <hip/hip_runtime.h>
#include <cmath>

#define B_ 64
#define L_ 200
#define H_ 128
#define S_ 64
#define E_ 256
#define K_ 101
#define NROW (B_ * L_)

__device__ __forceinline__ float wave_sum64(float v) {
#pragma unroll
  for (int o = 32; o > 0; o >>= 1) v += __shfl_xor(v, o, 64);
  return v;
}

__device__ __forceinline__ float block_sum_256(float v, volatile float* red) {
  v = wave_sum64(v);
  int w = threadIdx.x >> 6;
  __syncthreads();  // protect red reuse across calls
  if ((threadIdx.x & 63) == 0) red[w] = v;
  __syncthreads();
  return red[0] + red[1] + red[2] + red[3];
}

// x[b,l,h] = (item_emb[seq] + pos_emb[l]) * mask
__global__ void embed_kernel(const int* __restrict__ seqs, const float* __restrict__ emb,
                             const float* __restrict__ pos, float* __restrict__ x) {
  int r = blockIdx.x;          // b*L + l
  int h = threadIdx.x;         // 128
  int l = r % L_;
  int idx = seqs[r];
  float val = (idx != 0) ? (emb[(size_t)idx * H_ + h] + pos[l * H_ + h]) : 0.f;
  x[(size_t)r * H_ + h] = val;
}

// LayerNorm over H=128, one wave per row (2 elems/thread)
__global__ void ln_h_kernel(const float* __restrict__ x, const float* __restrict__ g,
                            const float* __restrict__ b, float* __restrict__ u) {
  int r = blockIdx.x;
  int t = threadIdx.x;  // 64
  float v0 = x[(size_t)r * H_ + t];
  float v1 = x[(size_t)r * H_ + 64 + t];
  float mean = wave_sum64(v0 + v1) * (1.f / 128.f);
  float d0 = v0 - mean, d1 = v1 - mean;
  float var = wave_sum64(d0 * d0 + d1 * d1) * (1.f / 128.f);
  float rs = rsqrtf(var + 1e-5f);
  u[(size_t)r * H_ + t]      = d0 * rs * g[t] + b[t];
  u[(size_t)r * H_ + 64 + t] = d1 * rs * g[64 + t] + b[64 + t];
}

// Final LN only at l = L-1, write xf[b,H]
__global__ void ln_final_kernel(const float* __restrict__ x, const float* __restrict__ g,
                                const float* __restrict__ b, float* __restrict__ xf) {
  int bb = blockIdx.x;
  int t = threadIdx.x;  // 64
  size_t r = (size_t)bb * L_ + (L_ - 1);
  float v0 = x[r * H_ + t];
  float v1 = x[r * H_ + 64 + t];
  float mean = wave_sum64(v0 + v1) * (1.f / 128.f);
  float d0 = v0 - mean, d1 = v1 - mean;
  float var = wave_sum64(d0 * d0 + d1 * d1) * (1.f / 128.f);
  float rs = rsqrtf(var + 1e-5f);
  xf[bb * H_ + t]      = d0 * rs * g[t] + b[t];
  xf[bb * H_ + 64 + t] = d1 * rs * g[64 + t] + b[64 + t];
}

// Tiled fp32 GEMM: C[M,N] = A[M,K] @ W[K,N] + bias
// EPI==1: C = (C_old + val) * mask[row]  (residual+mask epilogue)
template <int EPI>
__global__ __launch_bounds__(256) void gemm_kernel(
    const float* __restrict__ A, const float* __restrict__ W,
    const float* __restrict__ bias, float* __restrict__ C,
    int M, int N, int K, const int* __restrict__ seqs) {
  __shared__ float As[64][20];  // [m][k], pad to 20 for aligned float4 stores
  __shared__ float Bs[16][64];  // [k][n]
  const int tid = threadIdx.x;
  const int tx = tid & 15;   // n-dir
  const int ty = tid >> 4;   // m-dir
  const int m0 = blockIdx.y * 64;
  const int n0 = blockIdx.x * 64;

  const int a_m = tid >> 2;
  const int a_k = (tid & 3) << 2;
  const int b_k = tid >> 4;
  const int b_n = (tid & 15) << 2;

  float acc[4][4] = {{0.f, 0.f, 0.f, 0.f}, {0.f, 0.f, 0.f, 0.f},
                     {0.f, 0.f, 0.f, 0.f}, {0.f, 0.f, 0.f, 0.f}};

  for (int k0 = 0; k0 < K; k0 += 16) {
    float4 av = *(const float4*)(A + (size_t)(m0 + a_m) * K + k0 + a_k);
    float4 bv = *(const float4*)(W + (size_t)(b_k + k0) * N + n0 + b_n);
    *(float4*)&As[a_m][a_k] = av;
    *(float4*)&Bs[b_k][b_n] = bv;
    __syncthreads();
#pragma unroll
    for (int kk = 0; kk < 16; ++kk) {
      float4 b4 = *(const float4*)&Bs[kk][tx << 2];
      float a0 = As[ty * 4 + 0][kk];
      float a1 = As[ty * 4 + 1][kk];
      float a2 = As[ty * 4 + 2][kk];
      float a3 = As[ty * 4 + 3][kk];
      acc[0][0] += a0 * b4.x; acc[0][1] += a0 * b4.y; acc[0][2] += a0 * b4.z; acc[0][3] += a0 * b4.w;
      acc[1][0] += a1 * b4.x; acc[1][1] += a1 * b4.y; acc[1][2] += a1 * b4.z; acc[1][3] += a1 * b4.w;
      acc[2][0] += a2 * b4.x; acc[2][1] += a2 * b4.y; acc[2][2] += a2 * b4.z; acc[2][3] += a2 * b4.w;
      acc[3][0] += a3 * b4.x; acc[3][1] += a3 * b4.y; acc[3][2] += a3 * b4.z; acc[3][3] += a3 * b4.w;
    }
    __syncthreads();
  }

  float4 bz = *(const float4*)(bias + n0 + (tx << 2));
#pragma unroll
  for (int i = 0; i < 4; ++i) {
    int row = m0 + ty * 4 + i;
    float* cp = C + (size_t)row * N + n0 + (tx << 2);
    float4 val;
    val.x = acc[i][0] + bz.x;
    val.y = acc[i][1] + bz.y;
    val.z = acc[i][2] + bz.z;
    val.w = acc[i][3] + bz.w;
    if (EPI == 1) {
      float msk = (seqs[row] != 0) ? 1.f : 0.f;
      float4 old = *(const float4*)cp;
      val.x = (old.x + val.x) * msk;
      val.y = (old.y + val.y) * msk;
      val.z = (old.z + val.z) * msk;
      val.w = (old.w + val.w) * msk;
    }
    *(float4*)cp = val;
  }
}

// Depthwise conv (k=3, symmetric pad 1, cross-correlation) + bias + silu.
__global__ void conv_silu_kernel(const float* __restrict__ xz, const float* __restrict__ cw,
                                 const float* __restrict__ cb, float* __restrict__ xc,
                                 float* __restrict__ xsum) {
  __shared__ float red[4];
  int r = blockIdx.x;   // b*L + l
  int e = threadIdx.x;  // 256
  int l = r % L_;
  float w0 = cw[e * 3 + 0], w1 = cw[e * 3 + 1], w2 = cw[e * 3 + 2];
  float xm1 = (l > 0)      ? xz[(size_t)(r - 1) * 512 + e] : 0.f;
  float x0  =                xz[(size_t)r * 512 + e];
  float xp1 = (l < L_ - 1) ? xz[(size_t)(r + 1) * 512 + e] : 0.f;
  float v = w0 * xm1 + w1 * x0 + w2 * xp1 + cb[e];
  float sv = v / (1.f + expf(-v));  // silu
  xc[(size_t)r * E_ + e] = sv;
  float tot = block_sum_256(sv, red);
  if (threadIdx.x == 0) xsum[r] = tot;
}

// Sequential scan, collapsed state h[S] per batch. One WAVE per batch.
// v3: A2 hoisted into 64 VGPRs; h broadcast via LDS round-trip (b128 reads);
// 4 independent accumulators; per-step y-reduction removed — stores per-lane
// h*C to hc_out, reduced later inside gate_kernel.
__global__ __launch_bounds__(64) void scan_kernel(
    const float* __restrict__ ssm,   // [B*L, 192]: delta_raw | Bm | Cm
    const float* __restrict__ xs,    // [B*L]
    const float* __restrict__ A_log, // [S] (block-offset applied by caller)
    float* __restrict__ hc_out) {    // [B*L, 64] per-lane h*C
  __shared__ float hshare[64];
  const int b = blockIdx.x;
  const int i = threadIdx.x;  // 64
  const float LOG2E = 1.44269504088896340736f;
  const float LB = -14.4269504088896340736f;  // -10*log2e

  // A2_j = -exp(clip(A_log_j)) * log2e, broadcast into 64 VGPRs per lane
  float al = fminf(fmaxf(A_log[i], -5.f), 5.f);
  hshare[i] = -expf(al) * LOG2E;
  __syncthreads();
  float a2v[64];
#pragma unroll
  for (int g = 0; g < 16; ++g) {
    float4 q = *(const float4*)&hshare[g * 4];
    a2v[g * 4 + 0] = q.x; a2v[g * 4 + 1] = q.y;
    a2v[g * 4 + 2] = q.z; a2v[g * 4 + 3] = q.w;
  }
  __syncthreads();

  const float* base = ssm + (size_t)b * L_ * 192;
  const float* xsb = xs + b * L_;
  float* hcb = hc_out + (size_t)b * L_ * 64;

  float dr = base[i], bm = base[64 + i], cm = base[128 + i], xst = xsb[0];
  float h;
  {  // t = 0 (h starts at 0: no matvec)
    const float* r2 = base + 192;
    float dr2 = r2[i], bm2 = r2[64 + i], cm2 = r2[128 + i], xst2 = xsb[1];
    float d = fmaxf(dr, 0.f) + log1pf(__expf(-fabsf(dr)));
    h = fminf(fmaxf(d * bm * xst, -100.f), 100.f);
    hcb[i] = h * cm;
    dr = dr2; bm = bm2; cm = cm2; xst = xst2;
  }

  for (int t = 1; t < L_; ++t) {
    // prefetch step t+1 (independent of h)
    float dr2 = 0.f, bm2 = 0.f, cm2 = 0.f, xst2 = 0.f;
    if (t + 1 < L_) {
      const float* r2 = base + (size_t)(t + 1) * 192;
      dr2 = r2[i]; bm2 = r2[64 + i]; cm2 = r2[128 + i]; xst2 = xsb[t + 1];
    }
    float d = fmaxf(dr, 0.f) + log1pf(__expf(-fabsf(dr)));

    hshare[i] = h;
    __syncthreads();
    float acc0 = d * bm * xst, acc1 = 0.f, acc2 = 0.f, acc3 = 0.f;
#pragma unroll
    for (int g = 0; g < 16; ++g) {
      float4 hb = *(const float4*)&hshare[g * 4];
      float e0 = __builtin_amdgcn_exp2f(fmaxf(d * a2v[g * 4 + 0], LB));
      float e1 = __builtin_amdgcn_exp2f(fmaxf(d * a2v[g * 4 + 1], LB));
      float e2 = __builtin_amdgcn_exp2f(fmaxf(d * a2v[g * 4 + 2], LB));
      float e3 = __builtin_amdgcn_exp2f(fmaxf(d * a2v[g * 4 + 3], LB));
      acc0 += e0 * hb.x; acc1 += e1 * hb.y; acc2 += e2 * hb.z; acc3 += e3 * hb.w;
    }
    __syncthreads();
    h = fminf(fmaxf((acc0 + acc1) + (acc2 + acc3), -100.f), 100.f);
    hcb[(size_t)t * 64 + i] = h * cm;
    dr = dr2; bm = bm2; cm = cm2; xst = xst2;
  }
}

// s = sum(hc row); y = s + D*xc ; yln = LN_E(y) ; v = yln * silu(z)
// v may alias xc (each thread reads xc[r,e] before writing v[r,e]).
__global__ void gate_kernel(const float* __restrict__ hc, const float* __restrict__ xc,
                            const float* __restrict__ xz, const float* __restrict__ D,
                            const float* __restrict__ g, const float* __restrict__ bb,
                            float* __restrict__ v) {
  __shared__ float red[4];
  int r = blockIdx.x;
  int e = threadIdx.x;  // 256
  // each wave redundantly reduces the 64 hc values
  float s = wave_sum64(hc[(size_t)r * 64 + (e & 63)]);
  float y = s + D[e] * xc[(size_t)r * E_ + e];
  float mean = block_sum_256(y, red) * (1.f / 256.f);
  float d = y - mean;
  float var = block_sum_256(d * d, red) * (1.f / 256.f);
  float yln = d * rsqrtf(var + 1e-5f) * g[e] + bb[e];
  float z = xz[(size_t)r * 512 + 256 + e];
  v[(size_t)r * E_ + e] = yln * (z / (1.f + expf(-z)));
}

// logits[b,k] = xf[b,:] . item_emb[item_idxs[b,k], :]
__global__ void logits_kernel(const float* __restrict__ xf, const int* __restrict__ idxs,
                              const float* __restrict__ emb, float* __restrict__ out) {
  int p = blockIdx.x;  // b*K + k
  int b = p / K_;
  int t = threadIdx.x;  // 64
  int id = idxs[p];
  float a = xf[b * H_ + t] * emb[(size_t)id * H_ + t] +
            xf[b * H_ + 64 + t] * emb[(size_t)id * H_ + 64 + t];
  a = wave_sum64(a);
  if (t == 0) out[p] = a;
}

extern "C" void kernel_launch(void* const* d_in, const int* in_sizes, int n_in,
                              void* d_out, int out_size, void* d_ws, size_t ws_size,
                              hipStream_t stream) {
  const int*   seqs   = (const int*)d_in[0];
  const int*   idxs   = (const int*)d_in[1];
  const float* emb    = (const float*)d_in[2];
  const float* pos    = (const float*)d_in[3];
  const float* blk_g  = (const float*)d_in[4];
  const float* blk_b  = (const float*)d_in[5];
  const float* in_w   = (const float*)d_in[6];
  const float* in_b   = (const float*)d_in[7];
  const float* conv_w = (const float*)d_in[8];
  const float* conv_b = (const float*)d_in[9];
  const float* xp_w   = (const float*)d_in[10];
  const float* xp_b   = (const float*)d_in[11];
  const float* A_log  = (const float*)d_in[12];
  const float* D_p    = (const float*)d_in[13];
  const float* out_w  = (const float*)d_in[14];
  const float* out_b  = (const float*)d_in[15];
  const float* ig     = (const float*)d_in[16];
  const float* ib     = (const float*)d_in[17];
  const float* fg     = (const float*)d_in[18];
  const float* fb     = (const float*)d_in[19];
  float* out = (float*)d_out;
  float* ws = (float*)d_ws;

  // workspace layout (floats); v aliases xc (in-place gate). ~65.6 MB total.
  float* x   = ws;               // [12800,128]
  float* u   = ws + 1638400;     // [12800,128]
  float* xz  = ws + 3276800;     // [12800,512]
  float* xc  = ws + 9830400;     // [12800,256]
  float* ssm = ws + 13107200;    // [12800,192]
  float* xs  = ws + 15564800;    // [12800]
  float* hc  = ws + 15577600;    // [12800,64]
  float* xf  = ws + 16396800;    // [64,128]
  float* v   = xc;               // in-place

  embed_kernel<<<NROW, 128, 0, stream>>>(seqs, emb, pos, x);

  for (int blk = 0; blk < 2; ++blk) {
    ln_h_kernel<<<NROW, 64, 0, stream>>>(x, blk_g + blk * H_, blk_b + blk * H_, u);
    gemm_kernel<0><<<dim3(512 / 64, NROW / 64), 256, 0, stream>>>(
        u, in_w + (size_t)blk * H_ * 2 * E_, in_b + blk * 2 * E_, xz, NROW, 512, 128, nullptr);
    conv_silu_kernel<<<NROW, 256, 0, stream>>>(xz, conv_w + blk * E_ * 3, conv_b + blk * E_,
                                               xc, xs);
    gemm_kernel<0><<<dim3(192 / 64, NROW / 64), 256, 0, stream>>>(
        xc, xp_w + (size_t)blk * E_ * 3 * S_, xp_b + blk * 3 * S_, ssm, NROW, 192, 256, nullptr);
    scan_kernel<<<B_, 64, 0, stream>>>(ssm, xs, A_log + blk * S_, hc);
    gate_kernel<<<NROW, 256, 0, stream>>>(hc, xc, xz, D_p + blk * E_, ig + blk * E_,
                                          ib + blk * E_, v);
    gemm_kernel<1><<<dim3(128 / 64, NROW / 64), 256, 0, stream>>>(
        v, out_w + (size_t)blk * E_ * H_, out_b + blk * H_, x, NROW, 128, 256, seqs);
  }

  ln_final_kernel<<<B_, 64, 0, stream>>>(x, fg, fb, xf);
  logits_kernel<<<B_ * K_, 64, 0, stream>>>(xf, idxs, emb, out);
}